// Round 9
// baseline (185.152 us; speedup 1.0000x reference)
//
#include <hip/hip_runtime.h>
#include <hip/hip_bf16.h>

#define BB 8
#define TT 2048
#define DD 512
#define HH 4
#define DHH 64
#define INNER 256
#define N3 768

typedef __attribute__((ext_vector_type(8))) short bf16x8;
typedef __attribute__((ext_vector_type(4))) short bf16x4;
typedef __attribute__((ext_vector_type(4))) float f32x4;
typedef unsigned int u32;
typedef unsigned short u16;

static __device__ __forceinline__ u16 f2bf(float f) {
    u32 u = __float_as_uint(f);
    return (u16)((u + 0x7FFFu + ((u >> 16) & 1u)) >> 16);  // RNE
}

static __device__ __forceinline__ u32 pk2bf(float a, float b) {
    union { __hip_bfloat162 h; u32 u; } cv;
    cv.h = __float22bfloat162_rn(float2{a, b});
    return cv.u;
}

static __device__ __forceinline__ float exp2_hw(float x) {
    float r;
    asm("v_exp_f32 %0, %1" : "=v"(r) : "v"(x));
    return r;
}

static __device__ __forceinline__ void gl_lds16(const u16* g, u16* l) {
    __builtin_amdgcn_global_load_lds(
        (const __attribute__((address_space(1))) void*)g,
        (__attribute__((address_space(3))) void*)l, 16, 0, 0);
}

// ---------------------------------------------------------------------------
// Prep (fused): blocks [0,4096) cast x->bf16; [4096,4192) transpose w_qkv;
// [4192,4224) transpose w_out.
// ---------------------------------------------------------------------------
static __device__ void tcast_tile(const float* __restrict__ src, u16* __restrict__ dst,
                                  int R, int C, int tile) {
    __shared__ u16 Ts[64][72];
    const int tiles_c = C >> 6;
    const int r0 = (tile / tiles_c) * 64;
    const int c0 = (tile % tiles_c) * 64;
    const int row  = threadIdx.x >> 4;
    const int col4 = (threadIdx.x & 15) * 4;
#pragma unroll
    for (int rep = 0; rep < 4; ++rep) {
        const int r = row + rep * 16;
        const float4 a = *(const float4*)&src[(size_t)(r0 + r) * C + c0 + col4];
        Ts[col4 + 0][r] = f2bf(a.x);
        Ts[col4 + 1][r] = f2bf(a.y);
        Ts[col4 + 2][r] = f2bf(a.z);
        Ts[col4 + 3][r] = f2bf(a.w);
    }
    __syncthreads();
#pragma unroll
    for (int rep = 0; rep < 4; ++rep) {
        const int c = row + rep * 16;
        ushort4 v = {Ts[c][col4 + 0], Ts[c][col4 + 1], Ts[c][col4 + 2], Ts[c][col4 + 3]};
        *(ushort4*)&dst[(size_t)(c0 + c) * R + r0 + col4] = v;
    }
}

__global__ __launch_bounds__(256) void prep(const float* __restrict__ x,
                                            const float* __restrict__ wq,
                                            const float* __restrict__ wo,
                                            u16* __restrict__ xb,
                                            u16* __restrict__ wqT,
                                            u16* __restrict__ woT) {
    const int blk = blockIdx.x;
    if (blk < 4096) {
        const size_t i = ((size_t)blk * 256 + threadIdx.x) * 8;
        const float4 a = *(const float4*)&x[i];
        const float4 b = *(const float4*)&x[i + 4];
        ushort4 lo = {f2bf(a.x), f2bf(a.y), f2bf(a.z), f2bf(a.w)};
        ushort4 hi = {f2bf(b.x), f2bf(b.y), f2bf(b.z), f2bf(b.w)};
        *(ushort4*)&xb[i]     = lo;
        *(ushort4*)&xb[i + 4] = hi;
    } else if (blk < 4192) {
        tcast_tile(wq, wqT, DD, N3, blk - 4096);
    } else {
        tcast_tile(wo, woT, INNER, DD, blk - 4192);
    }
}

// ---------------------------------------------------------------------------
// Kernel 1: QKV projection, bf16 MFMA, double-buffered prefetch-before-compute.
// Q pre-scaled by 0.125*log2(e); q/k written (b,h,t,dh); V written TRANSPOSED
// (b,h,dh,t) via packed b64 stores.
// ---------------------------------------------------------------------------
__global__ __launch_bounds__(256) void qkv_mfma(const u16* __restrict__ xb,
                                                const u16* __restrict__ wT,
                                                u16* __restrict__ qb,
                                                u16* __restrict__ kb,
                                                u16* __restrict__ vtg) {
    __shared__ __align__(16) u16 As[2 * 4096];
    __shared__ __align__(16) u16 Bs[2 * 4096];
    const int tid  = threadIdx.x;
    const int wv   = tid >> 6;
    const int lane = tid & 63;
    const int quad = lane >> 4, l16 = lane & 15;
    const int m0 = blockIdx.y * 128, n0 = blockIdx.x * 128;
    const int lr = lane >> 2;
    const int lk = (lane & 3) * 8;

    f32x4 acc[4][4];
#pragma unroll
    for (int mt = 0; mt < 4; ++mt)
#pragma unroll
        for (int nt = 0; nt < 4; ++nt)
#pragma unroll
            for (int r = 0; r < 4; ++r) acc[mt][nt][r] = 0.f;

    const u16* ag = xb + (size_t)(m0 + wv * 16 + lr) * DD + lk;
    const u16* bg = wT + (size_t)(n0 + wv * 16 + lr) * DD + lk;

    gl_lds16(ag,                    As + (wv * 16) * 32);
    gl_lds16(ag + (size_t)64 * DD,  As + (64 + wv * 16) * 32);
    gl_lds16(bg,                    Bs + (wv * 16) * 32);
    gl_lds16(bg + (size_t)64 * DD,  Bs + (64 + wv * 16) * 32);
    __syncthreads();

    for (int it = 0; it < 16; ++it) {
        const int cb = it & 1;
        if (it < 15) {
            const int nb = cb ^ 1;
            const int k0 = (it + 1) * 32;
            gl_lds16(ag + k0,                   As + nb * 4096 + (wv * 16) * 32);
            gl_lds16(ag + k0 + (size_t)64 * DD, As + nb * 4096 + (64 + wv * 16) * 32);
            gl_lds16(bg + k0,                   Bs + nb * 4096 + (wv * 16) * 32);
            gl_lds16(bg + k0 + (size_t)64 * DD, Bs + nb * 4096 + (64 + wv * 16) * 32);
        }
        bf16x8 a[4], b[4];
#pragma unroll
        for (int mt = 0; mt < 4; ++mt)
            a[mt] = *(const bf16x8*)&As[cb * 4096 + ((wv >> 1) * 64 + mt * 16 + l16) * 32 + quad * 8];
#pragma unroll
        for (int nt = 0; nt < 4; ++nt)
            b[nt] = *(const bf16x8*)&Bs[cb * 4096 + ((wv & 1) * 64 + nt * 16 + l16) * 32 + quad * 8];
#pragma unroll
        for (int mt = 0; mt < 4; ++mt)
#pragma unroll
            for (int nt = 0; nt < 4; ++nt)
                acc[mt][nt] = __builtin_amdgcn_mfma_f32_16x16x32_bf16(a[mt], b[nt], acc[mt][nt], 0, 0, 0);
        __syncthreads();
    }

    const int which = n0 >> 8;  // 0=q 1=k 2=v
    const int b_ = m0 >> 11;
    if (which == 2) {
#pragma unroll
        for (int mt = 0; mt < 4; ++mt)
#pragma unroll
            for (int nt = 0; nt < 4; ++nt) {
                const int col = (wv & 1) * 64 + nt * 16 + l16;
                const int h   = ((n0 - 512) + col) >> 6;
                const int dh  = col & 63;
                const int t   = (m0 & 2047) + (wv >> 1) * 64 + mt * 16 + quad * 4;
                uint2 w = {pk2bf(acc[mt][nt][0], acc[mt][nt][1]),
                           pk2bf(acc[mt][nt][2], acc[mt][nt][3])};
                *(uint2*)&vtg[(((size_t)(b_ * HH + h) * DHH) + dh) * TT + t] = w;
            }
    } else {
        u16* dst = (which == 0) ? qb : kb;
        const float scl = (which == 0) ? 0.18033688011112042f : 1.0f;  // 0.125*log2e
#pragma unroll
        for (int mt = 0; mt < 4; ++mt)
#pragma unroll
            for (int nt = 0; nt < 4; ++nt) {
                const int n  = n0 + (wv & 1) * 64 + nt * 16 + l16;
                const int h  = (n & 255) >> 6;
                const int dh = n & 63;
#pragma unroll
                for (int r = 0; r < 4; ++r) {
                    const int t = (m0 & 2047) + (wv >> 1) * 64 + mt * 16 + quad * 4 + r;
                    dst[(((size_t)(b_ * HH + h) * TT) + t) * DHH + dh] = f2bf(acc[mt][nt][r] * scl);
                }
            }
    }
}

// ---------------------------------------------------------------------------
// Kernel 2: flash attention, S^T formulation, 64-q blocks, P via LDS (stride
// 36: conflict-free — the transport verified in R6; R7's bpermute reverted).
// Block: 64 q x one bh, 32 iters of 64 kv; 4 waves = (qh = wv&1: 32-q half) x
// (kh = wv>>1: 32-kv half).  Grid 1024; LDS 41984 B -> 3 blocks/CU.
// S^T = K.Q^T (C-layout: kv=mt*16+quad*4+r, q=nt*16+l16); P^T per-wave LDS
// [32 q][stride 36] (4 b64 writes + 4 b64 reads, wave-local, in-order DS).
// PV: O^T = V^T.P^T.  Constant-max softmax in exp2 domain (init -4*log2e).
// K/V^T dbuf 8KB tiles, XOR chunk swizzle, one barrier/iter.
// ---------------------------------------------------------------------------
__global__ __launch_bounds__(256) void attn_fwd(const u16* __restrict__ q,
                                                const u16* __restrict__ k,
                                                const u16* __restrict__ v,
                                                u16* __restrict__ o) {
    // u16 map: K[2][4096] @0, V^T[2][4096] @8192, P^T[4][32*36] @16384
    __shared__ __align__(16) u16 smem[20992];  // 41984 B
    const int tid  = threadIdx.x;
    const int wv   = tid >> 6;
    const int lane = tid & 63;
    const int quad = lane >> 4, l16 = lane & 15;
    const int qh   = wv & 1;
    const int kh   = wv >> 1;
    // XCD swizzle: id = xcd + 8*((bh&3)*32 + qt), xcd = bh>>2
    const int id  = blockIdx.x;
    const int k2  = id >> 3;
    const int bh  = ((id & 7) << 2) | (k2 >> 5);
    const int q0  = (k2 & 31) * 64;
    const u16* qp = q + (size_t)bh * TT * DHH;
    const u16* kp = k + (size_t)bh * TT * DHH;
    const u16* vp = v + (size_t)bh * DHH * TT;   // [dh][t]
    u16* opb = o + (size_t)(bh >> 2) * TT * INNER + (bh & 3) * DHH;

    // Q fragments (B-layout: n=l16 -> q row, k=quad*8+j -> dh)
    bf16x8 qf[2][2];
#pragma unroll
    for (int nt = 0; nt < 2; ++nt)
#pragma unroll
        for (int ks = 0; ks < 2; ++ks)
            qf[nt][ks] = *(const bf16x8*)&qp[(size_t)(q0 + qh * 32 + nt * 16 + l16) * DHH + ks * 32 + quad * 8];

    // staging lane constants (per gl_lds16: 8 rows x 8 chunk-swizzled cols)
    const int sr  = lane >> 3;                    // sub-row 0..7
    const int sc8 = ((lane & 7) ^ sr) << 3;       // source chunk (XOR swizzle)
    const u16* ks0 = kp + (size_t)(wv * 16 + sr) * DHH + sc8;
    const u16* vs0 = vp + (size_t)(wv * 16 + sr) * TT + sc8;
    u16* kdst = smem + (wv * 16) * 64;
    u16* vdst = smem + 8192 + (wv * 16) * 64;
    u16* pt   = smem + 16384 + wv * 1152;   // this wave's P^T [32 q][36]

    f32x4 oacc[4][2];   // [mt: dh tile][nt: q tile]
    float lsum[2] = {0.f, 0.f};
#pragma unroll
    for (int mt = 0; mt < 4; ++mt)
#pragma unroll
        for (int nt = 0; nt < 2; ++nt)
#pragma unroll
            for (int r = 0; r < 4; ++r) oacc[mt][nt][r] = 0.f;

    // prime buf 0 (kv tile 0)
    gl_lds16(ks0,                     kdst);
    gl_lds16(ks0 + (size_t)8 * DHH,   kdst + 512);
    gl_lds16(vs0,                     vdst);
    gl_lds16(vs0 + (size_t)8 * TT,    vdst + 512);
    __syncthreads();

    for (int it = 0; it < 32; ++it) {
        const int cb = it & 1;
        if (it < 31) {
            const int nb = cb ^ 1;
            const u16* kn = ks0 + (size_t)(it + 1) * 64 * DHH;
            const u16* vn = vs0 + (it + 1) * 64;
            gl_lds16(kn,                   kdst + nb * 4096);
            gl_lds16(kn + (size_t)8 * DHH, kdst + nb * 4096 + 512);
            gl_lds16(vn,                   vdst + nb * 4096);
            gl_lds16(vn + (size_t)8 * TT,  vdst + nb * 4096 + 512);
        }
        const u16* kt = smem + cb * 4096;
        const u16* vt = smem + 8192 + cb * 4096;

        // ---- S^T = K Q^T (wave: 32 kv x 32 q), init -4*log2e ----
        f32x4 sc[2][2];
#pragma unroll
        for (int mt = 0; mt < 2; ++mt)
#pragma unroll
            for (int nt = 0; nt < 2; ++nt)
#pragma unroll
                for (int r = 0; r < 4; ++r) sc[mt][nt][r] = -5.770780163555851f;
#pragma unroll
        for (int ks = 0; ks < 2; ++ks) {
            bf16x8 ak[2];
#pragma unroll
            for (int mt = 0; mt < 2; ++mt)
                ak[mt] = *(const bf16x8*)&kt[(kh * 32 + mt * 16 + l16) * 64 +
                                             (((ks * 4 + quad) ^ (l16 & 7)) << 3)];
#pragma unroll
            for (int mt = 0; mt < 2; ++mt)
#pragma unroll
                for (int nt = 0; nt < 2; ++nt)
                    sc[mt][nt] = __builtin_amdgcn_mfma_f32_16x16x32_bf16(ak[mt], qf[nt][ks], sc[mt][nt], 0, 0, 0);
        }

        // ---- p = 2^s; l partials; P^T b64 writes (stride 36, no conflicts) ----
#pragma unroll
        for (int mt = 0; mt < 2; ++mt)
#pragma unroll
            for (int nt = 0; nt < 2; ++nt) {
                const float p0 = exp2_hw(sc[mt][nt][0]);
                const float p1 = exp2_hw(sc[mt][nt][1]);
                const float p2 = exp2_hw(sc[mt][nt][2]);
                const float p3 = exp2_hw(sc[mt][nt][3]);
                lsum[nt] += (p0 + p1) + (p2 + p3);
                uint2 w = {pk2bf(p0, p1), pk2bf(p2, p3)};
                *(uint2*)&pt[(nt * 16 + l16) * 36 + mt * 16 + quad * 4] = w;
            }

        // ---- O^T += V^T P^T (wave-local P round trip, in-order DS) ----
        bf16x8 av[4], bp[2];
#pragma unroll
        for (int mt = 0; mt < 4; ++mt)
            av[mt] = *(const bf16x8*)&vt[(mt * 16 + l16) * 64 +
                                         (((kh * 4 + quad) ^ (l16 & 7)) << 3)];
#pragma unroll
        for (int nt = 0; nt < 2; ++nt) {
            union { bf16x8 v8; struct { bf16x4 lo, hi; } s; } u;
            u.s.lo = *(const bf16x4*)&pt[(nt * 16 + l16) * 36 + quad * 8];
            u.s.hi = *(const bf16x4*)&pt[(nt * 16 + l16) * 36 + quad * 8 + 4];
            bp[nt] = u.v8;
        }
#pragma unroll
        for (int mt = 0; mt < 4; ++mt)
#pragma unroll
            for (int nt = 0; nt < 2; ++nt)
                oacc[mt][nt] = __builtin_amdgcn_mfma_f32_16x16x32_bf16(av[mt], bp[nt], oacc[mt][nt], 0, 0, 0);
        __syncthreads();
    }

    // ---- l: reduce across quads (each quad holds a different kv chunk) ----
#pragma unroll
    for (int nt = 0; nt < 2; ++nt) {
        float s = lsum[nt];
        s += __shfl_xor(s, 16);
        s += __shfl_xor(s, 32);
        lsum[nt] = s;
    }

    // ---- cross-wave (kv-half) merge via LDS overlay ----
    __syncthreads();
    float* Osum = (float*)smem;                 // [qh][32 q][68]
    float* Ls   = (float*)smem + 2 * 32 * 68;   // [qh][32 q]
    if (kh == 1) {
#pragma unroll
        for (int mt = 0; mt < 4; ++mt)
#pragma unroll
            for (int nt = 0; nt < 2; ++nt)
                *(f32x4*)&Osum[qh * 2176 + (nt * 16 + l16) * 68 + mt * 16 + quad * 4] = oacc[mt][nt];
        if (quad == 0) {
#pragma unroll
            for (int nt = 0; nt < 2; ++nt) Ls[qh * 32 + nt * 16 + l16] = lsum[nt];
        }
    }
    __syncthreads();
    if (kh == 0) {
#pragma unroll
        for (int nt = 0; nt < 2; ++nt) {
            const float inv = 1.0f / (lsum[nt] + Ls[qh * 32 + nt * 16 + l16]);
            const int t_ = q0 + qh * 32 + nt * 16 + l16;
#pragma unroll
            for (int mt = 0; mt < 4; ++mt) {
                const f32x4 part = *(const f32x4*)&Osum[qh * 2176 + (nt * 16 + l16) * 68 + mt * 16 + quad * 4];
                const float v0 = (oacc[mt][nt][0] + part[0]) * inv;
                const float v1 = (oacc[mt][nt][1] + part[1]) * inv;
                const float v2 = (oacc[mt][nt][2] + part[2]) * inv;
                const float v3 = (oacc[mt][nt][3] + part[3]) * inv;
                uint2 w = {pk2bf(v0, v1), pk2bf(v2, v3)};
                *(uint2*)&opb[(size_t)t_ * INNER + mt * 16 + quad * 4] = w;
            }
        }
    }
}

// ---------------------------------------------------------------------------
// Kernel 3: out projection, bf16 MFMA, double-buffered prefetch, fused bias.
// ---------------------------------------------------------------------------
__global__ __launch_bounds__(256) void out_mfma(const u16* __restrict__ ob,
                                                const u16* __restrict__ wT,
                                                const float* __restrict__ bias,
                                                float* __restrict__ out) {
    __shared__ __align__(16) u16 As[2 * 4096];
    __shared__ __align__(16) u16 Bs[2 * 4096];
    const int tid  = threadIdx.x;
    const int wv   = tid >> 6;
    const int lane = tid & 63;
    const int quad = lane >> 4, l16 = lane & 15;
    const int m0 = blockIdx.y * 128, n0 = blockIdx.x * 128;
    const int lr = lane >> 2;
    const int lk = (lane & 3) * 8;

    f32x4 acc[4][4];
#pragma unroll
    for (int mt = 0; mt < 4; ++mt)
#pragma unroll
        for (int nt = 0; nt < 4; ++nt)
#pragma unroll
            for (int r = 0; r < 4; ++r) acc[mt][nt][r] = 0.f;

    const u16* ag = ob + (size_t)(m0 + wv * 16 + lr) * INNER + lk;
    const u16* bg = wT + (size_t)(n0 + wv * 16 + lr) * INNER + lk;

    gl_lds16(ag,                       As + (wv * 16) * 32);
    gl_lds16(ag + (size_t)64 * INNER,  As + (64 + wv * 16) * 32);
    gl_lds16(bg,                       Bs + (wv * 16) * 32);
    gl_lds16(bg + (size_t)64 * INNER,  Bs + (64 + wv * 16) * 32);
    __syncthreads();

    for (int it = 0; it < 8; ++it) {
        const int cb = it & 1;
        if (it < 7) {
            const int nb = cb ^ 1;
            const int k0 = (it + 1) * 32;
            gl_lds16(ag + k0,                      As + nb * 4096 + (wv * 16) * 32);
            gl_lds16(ag + k0 + (size_t)64 * INNER, As + nb * 4096 + (64 + wv * 16) * 32);
            gl_lds16(bg + k0,                      Bs + nb * 4096 + (wv * 16) * 32);
            gl_lds16(bg + k0 + (size_t)64 * INNER, Bs + nb * 4096 + (64 + wv * 16) * 32);
        }
        bf16x8 a[4], b[4];
#pragma unroll
        for (int mt = 0; mt < 4; ++mt)
            a[mt] = *(const bf16x8*)&As[cb * 4096 + ((wv >> 1) * 64 + mt * 16 + l16) * 32 + quad * 8];
#pragma unroll
        for (int nt = 0; nt < 4; ++nt)
            b[nt] = *(const bf16x8*)&Bs[cb * 4096 + ((wv & 1) * 64 + nt * 16 + l16) * 32 + quad * 8];
#pragma unroll
        for (int mt = 0; mt < 4; ++mt)
#pragma unroll
            for (int nt = 0; nt < 4; ++nt)
                acc[mt][nt] = __builtin_amdgcn_mfma_f32_16x16x32_bf16(a[mt], b[nt], acc[mt][nt], 0, 0, 0);
        __syncthreads();
    }

    float brow[4];
#pragma unroll
    for (int nt = 0; nt < 4; ++nt)
        brow[nt] = bias[n0 + (wv & 1) * 64 + nt * 16 + l16];
#pragma unroll
    for (int mt = 0; mt < 4; ++mt)
#pragma unroll
        for (int nt = 0; nt < 4; ++nt) {
            const int n = n0 + (wv & 1) * 64 + nt * 16 + l16;
#pragma unroll
            for (int r = 0; r < 4; ++r) {
                const int m = m0 + (wv >> 1) * 64 + mt * 16 + quad * 4 + r;
                out[(size_t)m * DD + n] = acc[mt][nt][r] + brow[nt];
            }
        }
}

extern "C" void kernel_launch(void* const* d_in, const int* in_sizes, int n_in,
                              void* d_out, int out_size, void* d_ws, size_t ws_size,
                              hipStream_t stream) {
    const float* x     = (const float*)d_in[0];
    const float* w_qkv = (const float*)d_in[1];
    const float* w_out = (const float*)d_in[2];
    const float* b_out = (const float*)d_in[3];
    float* out = (float*)d_out;

    u16* qb  = (u16*)d_ws;                 // 4,194,304 (b,h,t,dh), pre-scaled
    u16* kb  = qb  + (size_t)4194304;      // 4,194,304 (b,h,t,dh)
    u16* vtg = kb  + (size_t)4194304;      // 4,194,304 (b,h,dh,t) transposed
    u16* xb  = vtg + (size_t)4194304;      // 8,388,608 (x bf16; aliased by Ob)
    u16* wqT = xb  + (size_t)8388608;      // 768*512
    u16* woT = wqT + (size_t)393216;       // 512*256
    u16* Ob  = xb;                         // alias: xb dead after qkv_mfma
    // total ws use: ~43 MB

    prep<<<4224, 256, 0, stream>>>(x, w_qkv, w_out, xb, wqT, woT);
    qkv_mfma<<<dim3(6, 128), 256, 0, stream>>>(xb, wqT, qb, kb, vtg);
    attn_fwd<<<1024, 256, 0, stream>>>(qb, kb, vtg, Ob);
    out_mfma<<<dim3(4, 128), 256, 0, stream>>>(Ob, woT, b_out, out);
}

// Round 10
// 180.293 us; speedup vs baseline: 1.0270x; 1.0270x over previous
//
#include <hip/hip_runtime.h>
#include <hip/hip_bf16.h>

#define BB 8
#define TT 2048
#define DD 512
#define HH 4
#define DHH 64
#define INNER 256
#define N3 768

typedef __attribute__((ext_vector_type(8))) short bf16x8;
typedef __attribute__((ext_vector_type(4))) short bf16x4;
typedef __attribute__((ext_vector_type(4))) float f32x4;
typedef unsigned int u32;
typedef unsigned short u16;

static __device__ __forceinline__ u16 f2bf(float f) {
    u32 u = __float_as_uint(f);
    return (u16)((u + 0x7FFFu + ((u >> 16) & 1u)) >> 16);  // RNE
}

static __device__ __forceinline__ u32 pk2bf(float a, float b) {
    union { __hip_bfloat162 h; u32 u; } cv;
    cv.h = __float22bfloat162_rn(float2{a, b});
    return cv.u;
}

static __device__ __forceinline__ float exp2_hw(float x) {
    float r;
    asm("v_exp_f32 %0, %1" : "=v"(r) : "v"(x));
    return r;
}

static __device__ __forceinline__ void gl_lds16(const u16* g, u16* l) {
    __builtin_amdgcn_global_load_lds(
        (const __attribute__((address_space(1))) void*)g,
        (__attribute__((address_space(3))) void*)l, 16, 0, 0);
}

// ---------------------------------------------------------------------------
// Prep: weights only.  blocks [0,96) transpose w_qkv; [96,128) transpose w_out.
// ---------------------------------------------------------------------------
static __device__ void tcast_tile(const float* __restrict__ src, u16* __restrict__ dst,
                                  int R, int C, int tile) {
    __shared__ u16 Ts[64][72];
    const int tiles_c = C >> 6;
    const int r0 = (tile / tiles_c) * 64;
    const int c0 = (tile % tiles_c) * 64;
    const int row  = threadIdx.x >> 4;
    const int col4 = (threadIdx.x & 15) * 4;
#pragma unroll
    for (int rep = 0; rep < 4; ++rep) {
        const int r = row + rep * 16;
        const float4 a = *(const float4*)&src[(size_t)(r0 + r) * C + c0 + col4];
        Ts[col4 + 0][r] = f2bf(a.x);
        Ts[col4 + 1][r] = f2bf(a.y);
        Ts[col4 + 2][r] = f2bf(a.z);
        Ts[col4 + 3][r] = f2bf(a.w);
    }
    __syncthreads();
#pragma unroll
    for (int rep = 0; rep < 4; ++rep) {
        const int c = row + rep * 16;
        ushort4 v = {Ts[c][col4 + 0], Ts[c][col4 + 1], Ts[c][col4 + 2], Ts[c][col4 + 3]};
        *(ushort4*)&dst[(size_t)(c0 + c) * R + r0 + col4] = v;
    }
}

__global__ __launch_bounds__(256) void prep(const float* __restrict__ wq,
                                            const float* __restrict__ wo,
                                            u16* __restrict__ wqT,
                                            u16* __restrict__ woT) {
    const int blk = blockIdx.x;
    if (blk < 96) tcast_tile(wq, wqT, DD, N3, blk);
    else          tcast_tile(wo, woT, INNER, DD, blk - 96);
}

// ---------------------------------------------------------------------------
// Kernel 1: QKV projection, bf16 MFMA, double-buffered prefetch-before-compute.
// A is staged DIRECTLY from fp32 x (dwordx4 loads -> v_cvt_pk_bf16 ->
// ds_write_b128); B (transposed bf16 weights) via global_load_lds.
// Q pre-scaled by 0.125*log2(e); q/k written (b,h,t,dh); V written TRANSPOSED
// (b,h,dh,t) via packed b64 stores.
// ---------------------------------------------------------------------------
__global__ __launch_bounds__(256) void qkv_mfma(const float* __restrict__ x,
                                                const u16* __restrict__ wT,
                                                u16* __restrict__ qb,
                                                u16* __restrict__ kb,
                                                u16* __restrict__ vtg) {
    __shared__ __align__(16) u16 As[2 * 4096];
    __shared__ __align__(16) u16 Bs[2 * 4096];
    const int tid  = threadIdx.x;
    const int wv   = tid >> 6;
    const int lane = tid & 63;
    const int quad = lane >> 4, l16 = lane & 15;
    const int m0 = blockIdx.y * 128, n0 = blockIdx.x * 128;
    const int lr = lane >> 2;
    const int lk = (lane & 3) * 8;

    f32x4 acc[4][4];
#pragma unroll
    for (int mt = 0; mt < 4; ++mt)
#pragma unroll
        for (int nt = 0; nt < 4; ++nt)
#pragma unroll
            for (int r = 0; r < 4; ++r) acc[mt][nt][r] = 0.f;

    // A-staging lane constants: thread covers 16 k of one row
    const int arow = tid >> 1;
    const int ak16 = (tid & 1) << 4;
    const float* ax = x + (size_t)(m0 + arow) * DD + ak16;
    // B-staging (bf16 weights, async)
    const u16* bg = wT + (size_t)(n0 + wv * 16 + lr) * DD + lk;

    {   // prime buf 0
        const float4 a0 = *(const float4*)&ax[0];
        const float4 a1 = *(const float4*)&ax[4];
        const float4 a2 = *(const float4*)&ax[8];
        const float4 a3 = *(const float4*)&ax[12];
        gl_lds16(bg,                    Bs + (wv * 16) * 32);
        gl_lds16(bg + (size_t)64 * DD,  Bs + (64 + wv * 16) * 32);
        uint4 w0 = {pk2bf(a0.x, a0.y), pk2bf(a0.z, a0.w), pk2bf(a1.x, a1.y), pk2bf(a1.z, a1.w)};
        uint4 w1 = {pk2bf(a2.x, a2.y), pk2bf(a2.z, a2.w), pk2bf(a3.x, a3.y), pk2bf(a3.z, a3.w)};
        *(uint4*)&As[arow * 32 + ak16]     = w0;
        *(uint4*)&As[arow * 32 + ak16 + 8] = w1;
    }
    __syncthreads();

    for (int it = 0; it < 16; ++it) {
        const int cb = it & 1;
        float4 a0, a1, a2, a3;
        if (it < 15) {
            const int k0 = (it + 1) * 32;
            a0 = *(const float4*)&ax[k0];
            a1 = *(const float4*)&ax[k0 + 4];
            a2 = *(const float4*)&ax[k0 + 8];
            a3 = *(const float4*)&ax[k0 + 12];
            const int nb = cb ^ 1;
            gl_lds16(bg + k0,                   Bs + nb * 4096 + (wv * 16) * 32);
            gl_lds16(bg + k0 + (size_t)64 * DD, Bs + nb * 4096 + (64 + wv * 16) * 32);
        }
        bf16x8 a[4], b[4];
#pragma unroll
        for (int mt = 0; mt < 4; ++mt)
            a[mt] = *(const bf16x8*)&As[cb * 4096 + ((wv >> 1) * 64 + mt * 16 + l16) * 32 + quad * 8];
#pragma unroll
        for (int nt = 0; nt < 4; ++nt)
            b[nt] = *(const bf16x8*)&Bs[cb * 4096 + ((wv & 1) * 64 + nt * 16 + l16) * 32 + quad * 8];
#pragma unroll
        for (int mt = 0; mt < 4; ++mt)
#pragma unroll
            for (int nt = 0; nt < 4; ++nt)
                acc[mt][nt] = __builtin_amdgcn_mfma_f32_16x16x32_bf16(a[mt], b[nt], acc[mt][nt], 0, 0, 0);
        if (it < 15) {
            const int nb = cb ^ 1;
            uint4 w0 = {pk2bf(a0.x, a0.y), pk2bf(a0.z, a0.w), pk2bf(a1.x, a1.y), pk2bf(a1.z, a1.w)};
            uint4 w1 = {pk2bf(a2.x, a2.y), pk2bf(a2.z, a2.w), pk2bf(a3.x, a3.y), pk2bf(a3.z, a3.w)};
            *(uint4*)&As[nb * 4096 + arow * 32 + ak16]     = w0;
            *(uint4*)&As[nb * 4096 + arow * 32 + ak16 + 8] = w1;
        }
        __syncthreads();
    }

    const int which = n0 >> 8;  // 0=q 1=k 2=v
    const int b_ = m0 >> 11;
    if (which == 2) {
#pragma unroll
        for (int mt = 0; mt < 4; ++mt)
#pragma unroll
            for (int nt = 0; nt < 4; ++nt) {
                const int col = (wv & 1) * 64 + nt * 16 + l16;
                const int h   = ((n0 - 512) + col) >> 6;
                const int dh  = col & 63;
                const int t   = (m0 & 2047) + (wv >> 1) * 64 + mt * 16 + quad * 4;
                uint2 w = {pk2bf(acc[mt][nt][0], acc[mt][nt][1]),
                           pk2bf(acc[mt][nt][2], acc[mt][nt][3])};
                *(uint2*)&vtg[(((size_t)(b_ * HH + h) * DHH) + dh) * TT + t] = w;
            }
    } else {
        u16* dst = (which == 0) ? qb : kb;
        const float scl = (which == 0) ? 0.18033688011112042f : 1.0f;  // 0.125*log2e
#pragma unroll
        for (int mt = 0; mt < 4; ++mt)
#pragma unroll
            for (int nt = 0; nt < 4; ++nt) {
                const int n  = n0 + (wv & 1) * 64 + nt * 16 + l16;
                const int h  = (n & 255) >> 6;
                const int dh = n & 63;
#pragma unroll
                for (int r = 0; r < 4; ++r) {
                    const int t = (m0 & 2047) + (wv >> 1) * 64 + mt * 16 + quad * 4 + r;
                    dst[(((size_t)(b_ * HH + h) * TT) + t) * DHH + dh] = f2bf(acc[mt][nt][r] * scl);
                }
            }
    }
}

// ---------------------------------------------------------------------------
// Kernel 2: flash attention — exact R6 config (verified 62.6 us).
// Block: 128 q x one bh, 32 iters of 64 kv.  Waves: qh = wv&1 (64-q half),
// kh = wv>>1 (32-kv half) -> wave computes 64q x 32kv.  S^T = K.Q^T; P^T
// rows stride 36 u16 (conflict-free by phase analysis).  PV: O^T = V^T.P^T.
// Constant-max softmax in exp2 domain (acc init -4*log2e).  K/V^T dbuf 8KB
// tiles w/ XOR chunk swizzle; one barrier/iter.  LDS 50KB; grid 512.
// ---------------------------------------------------------------------------
__global__ __launch_bounds__(256) void attn_fwd(const u16* __restrict__ q,
                                                const u16* __restrict__ k,
                                                const u16* __restrict__ v,
                                                u16* __restrict__ o) {
    // u16 map: K[2][4096] @0, V^T[2][4096] @8192, P^T[4][64*36] @16384
    __shared__ __align__(16) u16 smem[25600];  // 50 KB
    const int tid  = threadIdx.x;
    const int wv   = tid >> 6;
    const int lane = tid & 63;
    const int quad = lane >> 4, l16 = lane & 15;
    const int qh   = wv & 1;
    const int kh   = wv >> 1;
    // XCD swizzle: id = xcd + 8*((bh&3)*16 + qt), xcd = bh>>2
    const int id  = blockIdx.x;
    const int k2  = id >> 3;
    const int bh  = ((id & 7) << 2) | (k2 >> 4);
    const int q0  = (k2 & 15) * 128;
    const u16* qp = q + (size_t)bh * TT * DHH;
    const u16* kp = k + (size_t)bh * TT * DHH;
    const u16* vp = v + (size_t)bh * DHH * TT;   // [dh][t]
    u16* opb = o + (size_t)(bh >> 2) * TT * INNER + (bh & 3) * DHH;

    // Q fragments (B-layout: n=l16 -> q row, k=quad*8+j -> dh)
    bf16x8 qf[4][2];
#pragma unroll
    for (int nt = 0; nt < 4; ++nt)
#pragma unroll
        for (int ks = 0; ks < 2; ++ks)
            qf[nt][ks] = *(const bf16x8*)&qp[(size_t)(q0 + qh * 64 + nt * 16 + l16) * DHH + ks * 32 + quad * 8];

    // staging lane constants (per gl_lds16: 8 rows x 8 chunk-swizzled cols)
    const int sr  = lane >> 3;                    // sub-row 0..7
    const int sc8 = ((lane & 7) ^ sr) << 3;       // source chunk (XOR swizzle)
    const u16* ks0 = kp + (size_t)(wv * 16 + sr) * DHH + sc8;
    const u16* vs0 = vp + (size_t)(wv * 16 + sr) * TT + sc8;
    u16* kdst = smem + (wv * 16) * 64;
    u16* vdst = smem + 8192 + (wv * 16) * 64;
    u16* pt   = smem + 16384 + wv * 2304;   // this wave's P^T [64 q][36]

    f32x4 oacc[4][4];   // [mt: dh tile][nt: q tile]
    float lsum[4] = {0.f, 0.f, 0.f, 0.f};
#pragma unroll
    for (int mt = 0; mt < 4; ++mt)
#pragma unroll
        for (int nt = 0; nt < 4; ++nt)
#pragma unroll
            for (int r = 0; r < 4; ++r) oacc[mt][nt][r] = 0.f;

    // prime buf 0 (kv tile 0)
    gl_lds16(ks0,                     kdst);
    gl_lds16(ks0 + (size_t)8 * DHH,   kdst + 512);
    gl_lds16(vs0,                     vdst);
    gl_lds16(vs0 + (size_t)8 * TT,    vdst + 512);
    __syncthreads();

    for (int it = 0; it < 32; ++it) {
        const int cb = it & 1;
        if (it < 31) {
            const int nb = cb ^ 1;
            const u16* kn = ks0 + (size_t)(it + 1) * 64 * DHH;
            const u16* vn = vs0 + (it + 1) * 64;
            gl_lds16(kn,                   kdst + nb * 4096);
            gl_lds16(kn + (size_t)8 * DHH, kdst + nb * 4096 + 512);
            gl_lds16(vn,                   vdst + nb * 4096);
            gl_lds16(vn + (size_t)8 * TT,  vdst + nb * 4096 + 512);
        }
        const u16* kt = smem + cb * 4096;
        const u16* vt = smem + 8192 + cb * 4096;

        // ---- S^T = K Q^T (wave: 32 kv x 64 q), init -4*log2e ----
        f32x4 sc[2][4];
#pragma unroll
        for (int mt = 0; mt < 2; ++mt)
#pragma unroll
            for (int nt = 0; nt < 4; ++nt)
#pragma unroll
                for (int r = 0; r < 4; ++r) sc[mt][nt][r] = -5.770780163555851f;
#pragma unroll
        for (int ks = 0; ks < 2; ++ks) {
            bf16x8 ak[2];
#pragma unroll
            for (int mt = 0; mt < 2; ++mt)
                ak[mt] = *(const bf16x8*)&kt[(kh * 32 + mt * 16 + l16) * 64 +
                                             (((ks * 4 + quad) ^ (l16 & 7)) << 3)];
#pragma unroll
            for (int mt = 0; mt < 2; ++mt)
#pragma unroll
                for (int nt = 0; nt < 4; ++nt)
                    sc[mt][nt] = __builtin_amdgcn_mfma_f32_16x16x32_bf16(ak[mt], qf[nt][ks], sc[mt][nt], 0, 0, 0);
        }

        // ---- p = 2^s; l partials; P^T b64 writes (stride 36: conflict-free) ----
#pragma unroll
        for (int mt = 0; mt < 2; ++mt)
#pragma unroll
            for (int nt = 0; nt < 4; ++nt) {
                const float p0 = exp2_hw(sc[mt][nt][0]);
                const float p1 = exp2_hw(sc[mt][nt][1]);
                const float p2 = exp2_hw(sc[mt][nt][2]);
                const float p3 = exp2_hw(sc[mt][nt][3]);
                lsum[nt] += (p0 + p1) + (p2 + p3);
                uint2 w = {pk2bf(p0, p1), pk2bf(p2, p3)};
                *(uint2*)&pt[(nt * 16 + l16) * 36 + mt * 16 + quad * 4] = w;
            }

        // ---- O^T += V^T P^T (wave-local P round trip, in-order DS) ----
        bf16x8 av[4], bp[4];
#pragma unroll
        for (int mt = 0; mt < 4; ++mt)
            av[mt] = *(const bf16x8*)&vt[(mt * 16 + l16) * 64 +
                                         (((kh * 4 + quad) ^ (l16 & 7)) << 3)];
#pragma unroll
        for (int nt = 0; nt < 4; ++nt) {
            union { bf16x8 v8; struct { bf16x4 lo, hi; } s; } u;
            u.s.lo = *(const bf16x4*)&pt[(nt * 16 + l16) * 36 + quad * 8];
            u.s.hi = *(const bf16x4*)&pt[(nt * 16 + l16) * 36 + quad * 8 + 4];
            bp[nt] = u.v8;
        }
#pragma unroll
        for (int mt = 0; mt < 4; ++mt)
#pragma unroll
            for (int nt = 0; nt < 4; ++nt)
                oacc[mt][nt] = __builtin_amdgcn_mfma_f32_16x16x32_bf16(av[mt], bp[nt], oacc[mt][nt], 0, 0, 0);
        __syncthreads();
    }

    // ---- l: reduce across quads (q col is quad-replicated after this) ----
#pragma unroll
    for (int nt = 0; nt < 4; ++nt) {
        float s = lsum[nt];
        s += __shfl_xor(s, 16);
        s += __shfl_xor(s, 32);
        lsum[nt] = s;
    }

    // ---- cross-wave (kv-half) merge via LDS overlay ----
    __syncthreads();
    float* Osum = (float*)smem;                 // [qh][64 q][68]
    float* Ls   = (float*)smem + 2 * 64 * 68;   // [qh][64 q]
    if (kh == 1) {
#pragma unroll
        for (int mt = 0; mt < 4; ++mt)
#pragma unroll
            for (int nt = 0; nt < 4; ++nt)
                *(f32x4*)&Osum[qh * 4352 + (nt * 16 + l16) * 68 + mt * 16 + quad * 4] = oacc[mt][nt];
        if (quad == 0) {
#pragma unroll
            for (int nt = 0; nt < 4; ++nt) Ls[qh * 64 + nt * 16 + l16] = lsum[nt];
        }
    }
    __syncthreads();
    if (kh == 0) {
#pragma unroll
        for (int nt = 0; nt < 4; ++nt) {
            const float inv = 1.0f / (lsum[nt] + Ls[qh * 64 + nt * 16 + l16]);
            const int t_ = q0 + qh * 64 + nt * 16 + l16;
#pragma unroll
            for (int mt = 0; mt < 4; ++mt) {
                const f32x4 part = *(const f32x4*)&Osum[qh * 4352 + (nt * 16 + l16) * 68 + mt * 16 + quad * 4];
                const float v0 = (oacc[mt][nt][0] + part[0]) * inv;
                const float v1 = (oacc[mt][nt][1] + part[1]) * inv;
                const float v2 = (oacc[mt][nt][2] + part[2]) * inv;
                const float v3 = (oacc[mt][nt][3] + part[3]) * inv;
                uint2 w = {pk2bf(v0, v1), pk2bf(v2, v3)};
                *(uint2*)&opb[(size_t)t_ * INNER + mt * 16 + quad * 4] = w;
            }
        }
    }
}

// ---------------------------------------------------------------------------
// Kernel 3: out projection, bf16 MFMA, double-buffered prefetch, fused bias.
// ---------------------------------------------------------------------------
__global__ __launch_bounds__(256) void out_mfma(const u16* __restrict__ ob,
                                                const u16* __restrict__ wT,
                                                const float* __restrict__ bias,
                                                float* __restrict__ out) {
    __shared__ __align__(16) u16 As[2 * 4096];
    __shared__ __align__(16) u16 Bs[2 * 4096];
    const int tid  = threadIdx.x;
    const int wv   = tid >> 6;
    const int lane = tid & 63;
    const int quad = lane >> 4, l16 = lane & 15;
    const int m0 = blockIdx.y * 128, n0 = blockIdx.x * 128;
    const int lr = lane >> 2;
    const int lk = (lane & 3) * 8;

    f32x4 acc[4][4];
#pragma unroll
    for (int mt = 0; mt < 4; ++mt)
#pragma unroll
        for (int nt = 0; nt < 4; ++nt)
#pragma unroll
            for (int r = 0; r < 4; ++r) acc[mt][nt][r] = 0.f;

    const u16* ag = ob + (size_t)(m0 + wv * 16 + lr) * INNER + lk;
    const u16* bg = wT + (size_t)(n0 + wv * 16 + lr) * INNER + lk;

    gl_lds16(ag,                       As + (wv * 16) * 32);
    gl_lds16(ag + (size_t)64 * INNER,  As + (64 + wv * 16) * 32);
    gl_lds16(bg,                       Bs + (wv * 16) * 32);
    gl_lds16(bg + (size_t)64 * INNER,  Bs + (64 + wv * 16) * 32);
    __syncthreads();

    for (int it = 0; it < 8; ++it) {
        const int cb = it & 1;
        if (it < 7) {
            const int nb = cb ^ 1;
            const int k0 = (it + 1) * 32;
            gl_lds16(ag + k0,                      As + nb * 4096 + (wv * 16) * 32);
            gl_lds16(ag + k0 + (size_t)64 * INNER, As + nb * 4096 + (64 + wv * 16) * 32);
            gl_lds16(bg + k0,                      Bs + nb * 4096 + (wv * 16) * 32);
            gl_lds16(bg + k0 + (size_t)64 * INNER, Bs + nb * 4096 + (64 + wv * 16) * 32);
        }
        bf16x8 a[4], b[4];
#pragma unroll
        for (int mt = 0; mt < 4; ++mt)
            a[mt] = *(const bf16x8*)&As[cb * 4096 + ((wv >> 1) * 64 + mt * 16 + l16) * 32 + quad * 8];
#pragma unroll
        for (int nt = 0; nt < 4; ++nt)
            b[nt] = *(const bf16x8*)&Bs[cb * 4096 + ((wv & 1) * 64 + nt * 16 + l16) * 32 + quad * 8];
#pragma unroll
        for (int mt = 0; mt < 4; ++mt)
#pragma unroll
            for (int nt = 0; nt < 4; ++nt)
                acc[mt][nt] = __builtin_amdgcn_mfma_f32_16x16x32_bf16(a[mt], b[nt], acc[mt][nt], 0, 0, 0);
        __syncthreads();
    }

    float brow[4];
#pragma unroll
    for (int nt = 0; nt < 4; ++nt)
        brow[nt] = bias[n0 + (wv & 1) * 64 + nt * 16 + l16];
#pragma unroll
    for (int mt = 0; mt < 4; ++mt)
#pragma unroll
        for (int nt = 0; nt < 4; ++nt) {
            const int n = n0 + (wv & 1) * 64 + nt * 16 + l16;
#pragma unroll
            for (int r = 0; r < 4; ++r) {
                const int m = m0 + (wv >> 1) * 64 + mt * 16 + quad * 4 + r;
                out[(size_t)m * DD + n] = acc[mt][nt][r] + brow[nt];
            }
        }
}

extern "C" void kernel_launch(void* const* d_in, const int* in_sizes, int n_in,
                              void* d_out, int out_size, void* d_ws, size_t ws_size,
                              hipStream_t stream) {
    const float* x     = (const float*)d_in[0];
    const float* w_qkv = (const float*)d_in[1];
    const float* w_out = (const float*)d_in[2];
    const float* b_out = (const float*)d_in[3];
    float* out = (float*)d_out;

    u16* qb  = (u16*)d_ws;                 // 4,194,304 (b,h,t,dh), pre-scaled
    u16* kb  = qb  + (size_t)4194304;      // 4,194,304 (b,h,t,dh)
    u16* vtg = kb  + (size_t)4194304;      // 4,194,304 (b,h,dh,t) transposed
    u16* Ob  = vtg + (size_t)4194304;      // 4,194,304 (b,t,inner)
    u16* wqT = Ob  + (size_t)4194304;      // 768*512
    u16* woT = wqT + (size_t)393216;       // 512*256
    // total ws use: ~34.6 MB

    prep<<<128, 256, 0, stream>>>(w_qkv, w_out, wqT, woT);
    qkv_mfma<<<dim3(6, 128), 256, 0, stream>>>(x, wqT, qb, kb, vtg);
    attn_fwd<<<512, 256, 0, stream>>>(qb, kb, vtg, Ob);
    out_mfma<<<dim3(4, 128), 256, 0, stream>>>(Ob, woT, b_out, out);
}